// Round 4
// baseline (745.723 us; speedup 1.0000x reference)
//
#include <hip/hip_runtime.h>
#include <hip/hip_cooperative_groups.h>

namespace cg = cooperative_groups;

#define HID 128
#define COOP_BLOCKS 1024  // 4 blk/CU: safely co-resident (1KB LDS, low VGPR)

typedef unsigned short ushort_t;
typedef unsigned int uint_t;
typedef float f32x4 __attribute__((ext_vector_type(4)));
typedef short s16x8 __attribute__((ext_vector_type(8)));

__device__ __forceinline__ ushort_t f2bf(float f) {
  uint_t u = __float_as_uint(f);
  uint_t r = (u + 0x7FFFu + ((u >> 16) & 1u)) >> 16;  // RNE
  return (ushort_t)r;
}
__device__ __forceinline__ float bfLo(uint_t v) { return __uint_as_float(v << 16); }
__device__ __forceinline__ float bfHi(uint_t v) { return __uint_as_float(v & 0xFFFF0000u); }

__device__ __forceinline__ uint4 pack8(const float4& lo, const float4& hi) {
  uint4 p;
  p.x = (uint_t)f2bf(lo.x) | ((uint_t)f2bf(lo.y) << 16);
  p.y = (uint_t)f2bf(lo.z) | ((uint_t)f2bf(lo.w) << 16);
  p.z = (uint_t)f2bf(hi.x) | ((uint_t)f2bf(hi.y) << 16);
  p.w = (uint_t)f2bf(hi.z) | ((uint_t)f2bf(hi.w) << 16);
  return p;
}

// ---------------- cooperative front-end ----------------
// R14: memset+prep+scan1+scan3+fill were 5 dispatches x ~8us gap; all fit the
// same launch shape (high occ, 1KB LDS). One cooperative kernel, 4 grid.sync.
// Cross-phase in-kernel data uses agent-scope atomics (XCD L2 non-coherence);
// data for later dispatches (hb/wsw/offsets/csr) relies on kernel-end flush.
__global__ __launch_bounds__(256) void front_kernel(
    const float* __restrict__ emb, const int* __restrict__ x,
    ushort_t* __restrict__ hb, int N,
    const float* __restrict__ Wl1, const float* __restrict__ Wr1,
    const float* __restrict__ Wl2, const float* __restrict__ Wr2,
    ushort_t* __restrict__ wsw,
    const int* __restrict__ srcI, const int* __restrict__ dstI, int E,
    int* __restrict__ deg, int* __restrict__ offsets,
    int* __restrict__ cursor, int* __restrict__ csr,
    int* __restrict__ blockSums) {
  cg::grid_group grid = cg::this_grid();
  __shared__ int s[256];
  const int t = threadIdx.x;
  const int b = blockIdx.x;
  const int gtid = b * 256 + t;
  const int gstride = COOP_BLOCKS * 256;

  // ---- phase A: zero deg + weight swizzle + 4-deep gather ----
  for (int i = gtid; i < N; i += gstride)
    __hip_atomic_store(&deg[i], 0, __ATOMIC_RELAXED, __HIP_MEMORY_SCOPE_AGENT);

  for (int i = gtid; i < 65536; i += gstride) {
    const float* srcs[4] = {Wl1, Wr1, Wl2, Wr2};
    int m = i >> 14, idx = i & 16383;
    int j = idx & 7;
    int lane = (idx >> 3) & 63;
    int nt = (idx >> 9) & 7;
    int ks = (idx >> 12) & 3;
    int row = nt * 16 + (lane & 15);
    int col = ks * 32 + (lane >> 4) * 8 + j;
    wsw[i] = f2bf(srcs[m][row * HID + col]);
  }

  const int qN = (N + 3) >> 2;
  for (int task = gtid; task < qN * 16; task += gstride) {
    int r0 = task >> 4, j = (task & 15) * 8;
    int r1 = r0 + qN, r2 = r0 + 2 * qN, r3 = r0 + 3 * qN;
    int s0 = x[r0];
    int s1 = (r1 < N) ? x[r1] : s0;
    int s2 = (r2 < N) ? x[r2] : s0;
    int s3 = (r3 < N) ? x[r3] : s0;
    const float* p0 = &emb[(size_t)s0 * HID + j];
    const float* p1 = &emb[(size_t)s1 * HID + j];
    const float* p2 = &emb[(size_t)s2 * HID + j];
    const float* p3 = &emb[(size_t)s3 * HID + j];
    float4 a0 = *(const float4*)p0, a1 = *(const float4*)(p0 + 4);
    float4 b0 = *(const float4*)p1, b1 = *(const float4*)(p1 + 4);
    float4 c0 = *(const float4*)p2, c1 = *(const float4*)(p2 + 4);
    float4 d0 = *(const float4*)p3, d1 = *(const float4*)(p3 + 4);
    *(uint4*)&hb[(size_t)r0 * HID + j] = pack8(a0, a1);
    if (r1 < N) *(uint4*)&hb[(size_t)r1 * HID + j] = pack8(b0, b1);
    if (r2 < N) *(uint4*)&hb[(size_t)r2 * HID + j] = pack8(c0, c1);
    if (r3 < N) *(uint4*)&hb[(size_t)r3 * HID + j] = pack8(d0, d1);
  }
  grid.sync();

  // ---- phase B: degree count ----
  for (int e = gtid; e < E; e += gstride) atomicAdd(&deg[dstI[e]], 1);
  grid.sync();

  // ---- phase C1: block-local scan, 256 nodes/block ----
  const int nChunks = (N + 255) >> 8;
  int myExcl = 0;
  if (b < nChunks) {
    int idx = b * 256 + t;
    int val = (idx < N)
        ? __hip_atomic_load(&deg[idx], __ATOMIC_RELAXED, __HIP_MEMORY_SCOPE_AGENT)
        : 0;
    s[t] = val;
    __syncthreads();
    for (int off = 1; off < 256; off <<= 1) {
      int v = (t >= off) ? s[t - off] : 0;
      __syncthreads();
      s[t] += v;
      __syncthreads();
    }
    myExcl = s[t] - val;
    if (t == 255)
      __hip_atomic_store(&blockSums[b], s[255], __ATOMIC_RELAXED,
                         __HIP_MEMORY_SCOPE_AGENT);
  }
  grid.sync();

  // ---- phase C2: cross-block prefix + write offsets/cursor ----
  if (b < nChunks) {
    int part = 0;
    for (int i = t; i < b; i += 256)
      part += __hip_atomic_load(&blockSums[i], __ATOMIC_RELAXED,
                                __HIP_MEMORY_SCOPE_AGENT);
    __syncthreads();  // done reading s from C1
    s[t] = part;
    __syncthreads();
    for (int off = 128; off > 0; off >>= 1) {
      if (t < off) s[t] += s[t + off];
      __syncthreads();
    }
    int prefix = s[0];
    int idx = b * 256 + t;
    if (idx < N) {
      int v = prefix + myExcl;
      offsets[idx] = v;  // consumed by later dispatches only
      __hip_atomic_store(&cursor[idx], v, __ATOMIC_RELAXED,
                         __HIP_MEMORY_SCOPE_AGENT);
    }
    if (b == 0 && t == 0) offsets[N] = E;
  }
  grid.sync();

  // ---- phase D: CSR fill ----
  for (int e = gtid; e < E; e += gstride) {
    int d = dstI[e];
    int pos = atomicAdd(&cursor[d], 1);
    csr[pos] = srcI[e];
  }
}

// ------- aggregate: one node per QUARTER-wave, masked 8-deep batch -------
// R11 lesson: gather-latency-bound, needs MAX occupancy -> standalone kernel.
// R13: masked 8-wide batch finishes deg<=8 (~85% at Poisson(6)) in ONE
// dependent csr->hb round; clamped duplicates hit the same cache line.
__global__ __launch_bounds__(256) void aggregate_kernel(
    const ushort_t* __restrict__ hb, const int* __restrict__ offsets,
    const int* __restrict__ csr, ushort_t* __restrict__ meanb, int N) {
  int t = threadIdx.x;
  int node = blockIdx.x * 16 + (t >> 4);
  if (node >= N) return;
  int l15 = t & 15;
  int o0 = offsets[node], o1 = offsets[node + 1];
  int last = o1 - 1;

  float acc[8];
#pragma unroll
  for (int i = 0; i < 8; i++) acc[i] = 0.f;

  for (int e = o0; e < o1; e += 8) {
    uint4 v[8];
    float m[8];
#pragma unroll
    for (int i = 0; i < 8; i++) {
      int idx = e + i;
      bool val = idx < o1;
      int sidx = csr[val ? idx : last];
      v[i] = *(const uint4*)&hb[(size_t)sidx * HID + l15 * 8];
      m[i] = val ? 1.f : 0.f;
    }
#pragma unroll
    for (int i = 0; i < 8; i++) {
      acc[0] = fmaf(m[i], bfLo(v[i].x), acc[0]);
      acc[1] = fmaf(m[i], bfHi(v[i].x), acc[1]);
      acc[2] = fmaf(m[i], bfLo(v[i].y), acc[2]);
      acc[3] = fmaf(m[i], bfHi(v[i].y), acc[3]);
      acc[4] = fmaf(m[i], bfLo(v[i].z), acc[4]);
      acc[5] = fmaf(m[i], bfHi(v[i].z), acc[5]);
      acc[6] = fmaf(m[i], bfLo(v[i].w), acc[6]);
      acc[7] = fmaf(m[i], bfHi(v[i].w), acc[7]);
    }
  }

  int d = o1 - o0;
  float inv = 1.0f / (float)(d > 1 ? d : 1);
  uint4 p;
  p.x = (uint_t)f2bf(acc[0] * inv) | ((uint_t)f2bf(acc[1] * inv) << 16);
  p.y = (uint_t)f2bf(acc[2] * inv) | ((uint_t)f2bf(acc[3] * inv) << 16);
  p.z = (uint_t)f2bf(acc[4] * inv) | ((uint_t)f2bf(acc[5] * inv) << 16);
  p.w = (uint_t)f2bf(acc[6] * inv) | ((uint_t)f2bf(acc[7] * inv) << 16);
  *(uint4*)&meanb[(size_t)node * HID + l15 * 8] = p;
}

// ---------------- MFMA GEMM (known-good): out = relu(mean@Wl^T + h@Wr^T + b) ----------------
// R13 lesson: single 64KB stage, ONE sync — both matrices' staging loads in
// flight together. (32KB half-staging exposed an L2 round-trip: 40->51us.)
__global__ __launch_bounds__(256) void mfma_gemm_kernel(
    const ushort_t* __restrict__ meanb, const ushort_t* __restrict__ hb,
    const ushort_t* __restrict__ WlS, const ushort_t* __restrict__ WrS,
    const float* __restrict__ bias, float* __restrict__ outF,
    ushort_t* __restrict__ outB, int N, int outIsBf16) {
  __shared__ ushort_t ws[32768];  // 64 KB: [0..16383]=Wl frags, rest = Wr
  const int t = threadIdx.x;
  const int wave = t >> 6;
  const int lane = t & 63;
  const int rowBase = (blockIdx.x * 4 + wave) * 32;
  const int l15 = lane & 15;
  const int quad = lane >> 4;
  const int kq = quad * 8;
  const bool active = rowBase < N;

  int r0 = rowBase + l15;       if (r0 >= N) r0 = N - 1;
  int r1 = rowBase + 16 + l15;  if (r1 >= N) r1 = N - 1;

  // A-frag prefetch (independent of LDS staging)
  s16x8 a[2][2][4];  // [half][rowgrp][ks]
  if (active) {
#pragma unroll
    for (int ks = 0; ks < 4; ks++) {
      a[0][0][ks] = *(const s16x8*)&meanb[(size_t)r0 * HID + ks * 32 + kq];
      a[0][1][ks] = *(const s16x8*)&meanb[(size_t)r1 * HID + ks * 32 + kq];
      a[1][0][ks] = *(const s16x8*)&hb[(size_t)r0 * HID + ks * 32 + kq];
      a[1][1][ks] = *(const s16x8*)&hb[(size_t)r1 * HID + ks * 32 + kq];
    }
  }

  // stage both weight matrices: contiguous 16B per thread, coalesced
#pragma unroll
  for (int it = 0; it < 8; it++) {
    int o = (it * 256 + t) * 8;
    *(s16x8*)&ws[o] = *(const s16x8*)&WlS[o];
    *(s16x8*)&ws[16384 + o] = *(const s16x8*)&WrS[o];
  }
  __syncthreads();

  if (active) {
    f32x4 acc[2][8];
#pragma unroll
    for (int mt = 0; mt < 2; mt++)
#pragma unroll
      for (int nt = 0; nt < 8; nt++) acc[mt][nt] = (f32x4){0.f, 0.f, 0.f, 0.f};

#pragma unroll
    for (int half = 0; half < 2; half++) {
      const int hbase = half * 16384;
#pragma unroll
      for (int ks = 0; ks < 4; ks++)
#pragma unroll
        for (int nt = 0; nt < 8; nt++) {
          s16x8 bfrag = *(const s16x8*)&ws[hbase + ((ks * 8 + nt) * 64 + lane) * 8];
          acc[0][nt] = __builtin_amdgcn_mfma_f32_16x16x32_bf16(a[half][0][ks], bfrag, acc[0][nt], 0, 0, 0);
          acc[1][nt] = __builtin_amdgcn_mfma_f32_16x16x32_bf16(a[half][1][ks], bfrag, acc[1][nt], 0, 0, 0);
        }
    }

#pragma unroll
    for (int mt = 0; mt < 2; mt++) {
#pragma unroll
      for (int nt = 0; nt < 8; nt++) {
        int col = nt * 16 + l15;
        float bv = bias[col];
#pragma unroll
        for (int r = 0; r < 4; r++) {
          int row = rowBase + mt * 16 + quad * 4 + r;
          if (row < N) {
            float v = fmaxf(acc[mt][nt][r] + bv, 0.f);
            if (outIsBf16) outB[(size_t)row * HID + col] = f2bf(v);
            else           outF[(size_t)row * HID + col] = v;
          }
        }
      }
    }
  }
}

extern "C" void kernel_launch(void* const* d_in, const int* in_sizes, int n_in,
                              void* d_out, int out_size, void* d_ws, size_t ws_size,
                              hipStream_t stream) {
  const int* x = (const int*)d_in[0];
  const int* ei = (const int*)d_in[1];
  const float* emb = (const float*)d_in[2];
  const float* Wl1 = (const float*)d_in[3];
  const float* bl1 = (const float*)d_in[4];
  const float* Wr1 = (const float*)d_in[5];
  const float* Wl2 = (const float*)d_in[6];
  const float* bl2 = (const float*)d_in[7];
  const float* Wr2 = (const float*)d_in[8];
  float* out = (float*)d_out;

  const int N = in_sizes[0];
  const int E = in_sizes[1] / 2;
  const int* srcI = ei;
  const int* dstI = ei + E;

  // workspace layout
  char* p = (char*)d_ws;
  ushort_t* hb = (ushort_t*)p;    p += (size_t)N * HID * sizeof(ushort_t);
  ushort_t* hb2 = (ushort_t*)p;   p += (size_t)N * HID * sizeof(ushort_t);
  ushort_t* meanb = (ushort_t*)p; p += (size_t)N * HID * sizeof(ushort_t);
  ushort_t* wb = (ushort_t*)p;    p += (size_t)4 * 16384 * sizeof(ushort_t);
  int* deg = (int*)p;             p += (size_t)((N + 3) & ~3) * sizeof(int);
  int* offsets = (int*)p;         p += (size_t)((N + 4) & ~3) * sizeof(int);
  int* cursor = (int*)p;          p += (size_t)((N + 3) & ~3) * sizeof(int);
  int* csr = (int*)p;             p += (size_t)((E + 3) & ~3) * sizeof(int);
  int* blockSums = (int*)p;       p += 512 * sizeof(int);

  ushort_t* Wlb1 = wb;
  ushort_t* Wrb1 = wb + 16384;
  ushort_t* Wlb2 = wb + 32768;
  ushort_t* Wrb2 = wb + 49152;

  const int gemmBlocks = (N + 127) / 128;
  const int aggBlocks = (N + 15) / 16;

  // ---- fused front-end: zero+gather+swizzle+degcount+scan+fill (1 dispatch) ----
  {
    // non-const locals so &arg types are stable
    const float* a_emb = emb; const int* a_x = x;
    ushort_t* a_hb = hb; int a_N = N;
    const float* a_Wl1 = Wl1; const float* a_Wr1 = Wr1;
    const float* a_Wl2 = Wl2; const float* a_Wr2 = Wr2;
    ushort_t* a_wsw = wb;
    const int* a_src = srcI; const int* a_dst = dstI; int a_E = E;
    int* a_deg = deg; int* a_off = offsets; int* a_cur = cursor;
    int* a_csr = csr; int* a_bs = blockSums;
    void* args[] = {&a_emb, &a_x, &a_hb, &a_N, &a_Wl1, &a_Wr1, &a_Wl2, &a_Wr2,
                    &a_wsw, &a_src, &a_dst, &a_E, &a_deg, &a_off, &a_cur,
                    &a_csr, &a_bs};
    hipLaunchCooperativeKernel((void*)front_kernel, dim3(COOP_BLOCKS),
                               dim3(256), args, 0, stream);
  }

  // ---- layer 1: hb -> hb2 (bf16) ----
  aggregate_kernel<<<aggBlocks, 256, 0, stream>>>(hb, offsets, csr, meanb, N);
  mfma_gemm_kernel<<<gemmBlocks, 256, 0, stream>>>(meanb, hb, Wlb1, Wrb1, bl1,
                                                   nullptr, hb2, N, 1);

  // ---- layer 2: hb2 -> out (f32) ----
  aggregate_kernel<<<aggBlocks, 256, 0, stream>>>(hb2, offsets, csr, meanb, N);
  mfma_gemm_kernel<<<gemmBlocks, 256, 0, stream>>>(meanb, hb2, Wlb2, Wrb2, bl2,
                                                   out, nullptr, N, 0);
}

// Round 5
// 311.524 us; speedup vs baseline: 2.3938x; 2.3938x over previous
//
#include <hip/hip_runtime.h>

#define HID 128

typedef unsigned short ushort_t;
typedef unsigned int uint_t;
typedef float f32x4 __attribute__((ext_vector_type(4)));
typedef short s16x8 __attribute__((ext_vector_type(8)));

__device__ __forceinline__ ushort_t f2bf(float f) {
  uint_t u = __float_as_uint(f);
  uint_t r = (u + 0x7FFFu + ((u >> 16) & 1u)) >> 16;  // RNE
  return (ushort_t)r;
}
__device__ __forceinline__ float bfLo(uint_t v) { return __uint_as_float(v << 16); }
__device__ __forceinline__ float bfHi(uint_t v) { return __uint_as_float(v & 0xFFFF0000u); }

__device__ __forceinline__ uint4 pack8(const float4& lo, const float4& hi) {
  uint4 p;
  p.x = (uint_t)f2bf(lo.x) | ((uint_t)f2bf(lo.y) << 16);
  p.y = (uint_t)f2bf(lo.z) | ((uint_t)f2bf(lo.w) << 16);
  p.z = (uint_t)f2bf(hi.x) | ((uint_t)f2bf(hi.y) << 16);
  p.w = (uint_t)f2bf(hi.z) | ((uint_t)f2bf(hi.w) << 16);
  return p;
}

// ------- fused prep: 8-deep gather + weight-swizzle + degree count -------
// R9: 1-deep = 43us. R12: 4-deep ~= 30-40us, VALUBusy 3.6 -> still
// latency-bound. R15: 8 rows/thread, all x-loads made independent via CLAMP
// (not fallback-to-s0, which would serialize on the first load).
// R14 lesson: do NOT fuse this via grid.sync -- coop barrier cost ~100us/sync.
__global__ __launch_bounds__(256) void prep_kernel(
    const float* __restrict__ emb, const int* __restrict__ x,
    ushort_t* __restrict__ hb, int N,
    const float* __restrict__ Wl1, const float* __restrict__ Wr1,
    const float* __restrict__ Wl2, const float* __restrict__ Wr2,
    ushort_t* __restrict__ wsw,
    const int* __restrict__ dst, int* __restrict__ deg, int E) {
  int tid = blockIdx.x * 256 + threadIdx.x;
  const int eN = (N + 7) >> 3;
  int gthreads = eN * 16;
  if (tid < gthreads) {
    int r0 = tid >> 4, j = (tid & 15) * 8;
    int rs[8], si[8];
#pragma unroll
    for (int k = 0; k < 8; k++) {
      int r = r0 + k * eN;
      rs[k] = r;
      int rc = (r < N) ? r : N - 1;
      si[k] = x[rc];  // 8 independent loads
    }
    float4 lo[8], hi[8];
#pragma unroll
    for (int k = 0; k < 8; k++) {
      const float* pk = &emb[(size_t)si[k] * HID + j];
      lo[k] = *(const float4*)pk;
      hi[k] = *(const float4*)(pk + 4);
    }
#pragma unroll
    for (int k = 0; k < 8; k++) {
      if (rs[k] < N)
        *(uint4*)&hb[(size_t)rs[k] * HID + j] = pack8(lo[k], hi[k]);
    }
    return;
  }
  tid -= gthreads;
  if (tid < 65536) {
    const float* srcs[4] = {Wl1, Wr1, Wl2, Wr2};
    int m = tid >> 14, idx = tid & 16383;
    int j = idx & 7;
    int lane = (idx >> 3) & 63;
    int nt = (idx >> 9) & 7;
    int ks = (idx >> 12) & 3;
    int row = nt * 16 + (lane & 15);
    int col = ks * 32 + (lane >> 4) * 8 + j;
    wsw[tid] = f2bf(srcs[m][row * HID + col]);
    return;
  }
  tid -= 65536;
  if (tid < E) atomicAdd(&deg[dst[tid]], 1);
}

// ---------------- CSR build ----------------
__global__ __launch_bounds__(256) void scan1_kernel(
    const int* __restrict__ deg, int* __restrict__ offsets,
    int* __restrict__ sums, int N) {
  __shared__ int s[256];
  int b = blockIdx.x, t = threadIdx.x;
  int base = b * 1024 + t * 4;
  int v0 = 0, v1 = 0, v2 = 0, v3 = 0;
  if (base + 0 < N) v0 = deg[base + 0];
  if (base + 1 < N) v1 = deg[base + 1];
  if (base + 2 < N) v2 = deg[base + 2];
  if (base + 3 < N) v3 = deg[base + 3];
  int mySum = v0 + v1 + v2 + v3;
  s[t] = mySum;
  __syncthreads();
  for (int off = 1; off < 256; off <<= 1) {
    int v = (t >= off) ? s[t - off] : 0;
    __syncthreads();
    s[t] += v;
    __syncthreads();
  }
  int excl = s[t] - mySum;
  if (t == 255) sums[b] = s[255];
  if (base + 0 < N) offsets[base + 0] = excl;
  if (base + 1 < N) offsets[base + 1] = excl + v0;
  if (base + 2 < N) offsets[base + 2] = excl + v0 + v1;
  if (base + 3 < N) offsets[base + 3] = excl + v0 + v1 + v2;
}

__global__ __launch_bounds__(256) void scan3_kernel(
    int* __restrict__ offsets, const int* __restrict__ sums,
    int* __restrict__ cursor, int N, int E, int nb) {
  __shared__ int red[256];
  int t = threadIdx.x;
  int chunk = (blockIdx.x * 256) >> 10;
  red[t] = (t < chunk) ? sums[t] : 0;
  __syncthreads();
  for (int off = 128; off > 0; off >>= 1) {
    if (t < off) red[t] += red[t + off];
    __syncthreads();
  }
  int prefix = red[0];
  int i = blockIdx.x * 256 + t;
  if (i < N) {
    int v = offsets[i] + prefix;
    offsets[i] = v;
    cursor[i] = v;
  } else if (i == N) {
    offsets[N] = E;
  }
}

__global__ __launch_bounds__(256) void fill_kernel(
    const int* __restrict__ src, const int* __restrict__ dst,
    int* __restrict__ cursor, int* __restrict__ csr, int E) {
  int e = blockIdx.x * 256 + threadIdx.x;
  if (e >= E) return;
  int d = dst[e];
  int pos = atomicAdd(&cursor[d], 1);
  csr[pos] = src[e];
}

// ------- aggregate: one node per QUARTER-wave, masked 8-deep batch -------
// R11 lesson: gather-latency-bound, needs MAX occupancy -> standalone kernel.
// R13: masked 8-wide batch finishes deg<=8 (~85% at Poisson(6)) in ONE
// dependent csr->hb round; clamped duplicates hit the same cache line.
__global__ __launch_bounds__(256) void aggregate_kernel(
    const ushort_t* __restrict__ hb, const int* __restrict__ offsets,
    const int* __restrict__ csr, ushort_t* __restrict__ meanb, int N) {
  int t = threadIdx.x;
  int node = blockIdx.x * 16 + (t >> 4);
  if (node >= N) return;
  int l15 = t & 15;
  int o0 = offsets[node], o1 = offsets[node + 1];
  int last = o1 - 1;

  float acc[8];
#pragma unroll
  for (int i = 0; i < 8; i++) acc[i] = 0.f;

  for (int e = o0; e < o1; e += 8) {
    uint4 v[8];
    float m[8];
#pragma unroll
    for (int i = 0; i < 8; i++) {
      int idx = e + i;
      bool val = idx < o1;
      int sidx = csr[val ? idx : last];
      v[i] = *(const uint4*)&hb[(size_t)sidx * HID + l15 * 8];
      m[i] = val ? 1.f : 0.f;
    }
#pragma unroll
    for (int i = 0; i < 8; i++) {
      acc[0] = fmaf(m[i], bfLo(v[i].x), acc[0]);
      acc[1] = fmaf(m[i], bfHi(v[i].x), acc[1]);
      acc[2] = fmaf(m[i], bfLo(v[i].y), acc[2]);
      acc[3] = fmaf(m[i], bfHi(v[i].y), acc[3]);
      acc[4] = fmaf(m[i], bfLo(v[i].z), acc[4]);
      acc[5] = fmaf(m[i], bfHi(v[i].z), acc[5]);
      acc[6] = fmaf(m[i], bfLo(v[i].w), acc[6]);
      acc[7] = fmaf(m[i], bfHi(v[i].w), acc[7]);
    }
  }

  int d = o1 - o0;
  float inv = 1.0f / (float)(d > 1 ? d : 1);
  uint4 p;
  p.x = (uint_t)f2bf(acc[0] * inv) | ((uint_t)f2bf(acc[1] * inv) << 16);
  p.y = (uint_t)f2bf(acc[2] * inv) | ((uint_t)f2bf(acc[3] * inv) << 16);
  p.z = (uint_t)f2bf(acc[4] * inv) | ((uint_t)f2bf(acc[5] * inv) << 16);
  p.w = (uint_t)f2bf(acc[6] * inv) | ((uint_t)f2bf(acc[7] * inv) << 16);
  *(uint4*)&meanb[(size_t)node * HID + l15 * 8] = p;
}

// ---------------- MFMA GEMM: out = relu(mean@Wl^T + h@Wr^T + b) ----------------
// R13 lesson: single 64KB stage, ONE sync (both matrices' staging in flight).
// R15: 2 row-tiles per wave (64 rows). R3 counters: 38us, 994GB/s, MfmaUtil
// 4.3% -> latency-bound at 16 loads in flight/wave. Prefetch BOTH tiles' A
// frags up front (32 loads in flight), amortize the weight stage over 256
// rows, reuse acc between tiles. VGPR ~200 -> still 2 waves/SIMD (LDS-bound
// at 8 waves/CU anyway).
__global__ __launch_bounds__(256) void mfma_gemm_kernel(
    const ushort_t* __restrict__ meanb, const ushort_t* __restrict__ hb,
    const ushort_t* __restrict__ WlS, const ushort_t* __restrict__ WrS,
    const float* __restrict__ bias, float* __restrict__ outF,
    ushort_t* __restrict__ outB, int N, int outIsBf16) {
  __shared__ ushort_t ws[32768];  // 64 KB: [0..16383]=Wl frags, rest = Wr
  const int t = threadIdx.x;
  const int wave = t >> 6;
  const int lane = t & 63;
  const int tileBase = (blockIdx.x * 4 + wave) * 64;  // 2 tiles of 32 rows
  const int l15 = lane & 15;
  const int quad = lane >> 4;
  const int kq = quad * 8;

  // A-frag prefetch for both tiles (independent of LDS staging)
  s16x8 a[2][2][2][4];  // [tile][half][rowgrp][ks]
#pragma unroll
  for (int tl = 0; tl < 2; tl++) {
    int rb = tileBase + tl * 32;
    if (rb >= N) break;
    int r0 = rb + l15;       if (r0 >= N) r0 = N - 1;
    int r1 = rb + 16 + l15;  if (r1 >= N) r1 = N - 1;
#pragma unroll
    for (int ks = 0; ks < 4; ks++) {
      a[tl][0][0][ks] = *(const s16x8*)&meanb[(size_t)r0 * HID + ks * 32 + kq];
      a[tl][0][1][ks] = *(const s16x8*)&meanb[(size_t)r1 * HID + ks * 32 + kq];
      a[tl][1][0][ks] = *(const s16x8*)&hb[(size_t)r0 * HID + ks * 32 + kq];
      a[tl][1][1][ks] = *(const s16x8*)&hb[(size_t)r1 * HID + ks * 32 + kq];
    }
  }

  // stage both weight matrices: contiguous 16B per thread, coalesced
#pragma unroll
  for (int it = 0; it < 8; it++) {
    int o = (it * 256 + t) * 8;
    *(s16x8*)&ws[o] = *(const s16x8*)&WlS[o];
    *(s16x8*)&ws[16384 + o] = *(const s16x8*)&WrS[o];
  }
  __syncthreads();

#pragma unroll
  for (int tl = 0; tl < 2; tl++) {
    int rowBase = tileBase + tl * 32;
    if (rowBase >= N) break;

    f32x4 acc[2][8];
#pragma unroll
    for (int mt = 0; mt < 2; mt++)
#pragma unroll
      for (int nt = 0; nt < 8; nt++) acc[mt][nt] = (f32x4){0.f, 0.f, 0.f, 0.f};

#pragma unroll
    for (int half = 0; half < 2; half++) {
      const int hbase = half * 16384;
#pragma unroll
      for (int ks = 0; ks < 4; ks++)
#pragma unroll
        for (int nt = 0; nt < 8; nt++) {
          s16x8 bfrag = *(const s16x8*)&ws[hbase + ((ks * 8 + nt) * 64 + lane) * 8];
          acc[0][nt] = __builtin_amdgcn_mfma_f32_16x16x32_bf16(a[tl][half][0][ks], bfrag, acc[0][nt], 0, 0, 0);
          acc[1][nt] = __builtin_amdgcn_mfma_f32_16x16x32_bf16(a[tl][half][1][ks], bfrag, acc[1][nt], 0, 0, 0);
        }
    }

#pragma unroll
    for (int mt = 0; mt < 2; mt++) {
#pragma unroll
      for (int nt = 0; nt < 8; nt++) {
        int col = nt * 16 + l15;
        float bv = bias[col];
#pragma unroll
        for (int r = 0; r < 4; r++) {
          int row = rowBase + mt * 16 + quad * 4 + r;
          if (row < N) {
            float v = fmaxf(acc[mt][nt][r] + bv, 0.f);
            if (outIsBf16) outB[(size_t)row * HID + col] = f2bf(v);
            else           outF[(size_t)row * HID + col] = v;
          }
        }
      }
    }
  }
}

extern "C" void kernel_launch(void* const* d_in, const int* in_sizes, int n_in,
                              void* d_out, int out_size, void* d_ws, size_t ws_size,
                              hipStream_t stream) {
  const int* x = (const int*)d_in[0];
  const int* ei = (const int*)d_in[1];
  const float* emb = (const float*)d_in[2];
  const float* Wl1 = (const float*)d_in[3];
  const float* bl1 = (const float*)d_in[4];
  const float* Wr1 = (const float*)d_in[5];
  const float* Wl2 = (const float*)d_in[6];
  const float* bl2 = (const float*)d_in[7];
  const float* Wr2 = (const float*)d_in[8];
  float* out = (float*)d_out;

  const int N = in_sizes[0];
  const int E = in_sizes[1] / 2;
  const int* srcI = ei;
  const int* dstI = ei + E;

  // workspace layout
  char* p = (char*)d_ws;
  ushort_t* hb = (ushort_t*)p;    p += (size_t)N * HID * sizeof(ushort_t);
  ushort_t* hb2 = (ushort_t*)p;   p += (size_t)N * HID * sizeof(ushort_t);
  ushort_t* meanb = (ushort_t*)p; p += (size_t)N * HID * sizeof(ushort_t);
  ushort_t* wb = (ushort_t*)p;    p += (size_t)4 * 16384 * sizeof(ushort_t);
  int* deg = (int*)p;             p += (size_t)((N + 3) & ~3) * sizeof(int);
  int* offsets = (int*)p;         p += (size_t)((N + 4) & ~3) * sizeof(int);
  int* cursor = (int*)p;          p += (size_t)((N + 3) & ~3) * sizeof(int);
  int* csr = (int*)p;             p += (size_t)((E + 3) & ~3) * sizeof(int);
  int* sums = (int*)p;            p += 256 * sizeof(int);

  ushort_t* Wlb1 = wb;
  ushort_t* Wrb1 = wb + 16384;
  ushort_t* Wlb2 = wb + 32768;
  ushort_t* Wrb2 = wb + 49152;

  const int nScanBlocks = (N + 1023) / 1024;  // <=256 required
  const int eBlocks = (E + 255) / 256;
  const int gemmBlocks = (N + 255) / 256;     // 256 rows/block (2 tiles/wave)
  const int aggBlocks = (N + 15) / 16;
  const int eN = (N + 7) / 8;
  const int prepBlocks = (eN * 16 + 65536 + E + 255) / 256;

  // ---- CSR build + conversions ----
  hipMemsetAsync(deg, 0, (size_t)N * sizeof(int), stream);
  prep_kernel<<<prepBlocks, 256, 0, stream>>>(emb, x, hb, N,
                                              Wl1, Wr1, Wl2, Wr2, wb,
                                              dstI, deg, E);
  scan1_kernel<<<nScanBlocks, 256, 0, stream>>>(deg, offsets, sums, N);
  scan3_kernel<<<(N + 256) / 256, 256, 0, stream>>>(offsets, sums, cursor,
                                                    N, E, nScanBlocks);
  fill_kernel<<<eBlocks, 256, 0, stream>>>(srcI, dstI, cursor, csr, E);

  // ---- layer 1: hb -> hb2 (bf16) ----
  aggregate_kernel<<<aggBlocks, 256, 0, stream>>>(hb, offsets, csr, meanb, N);
  mfma_gemm_kernel<<<gemmBlocks, 256, 0, stream>>>(meanb, hb, Wlb1, Wrb1, bl1,
                                                   nullptr, hb2, N, 1);

  // ---- layer 2: hb2 -> out (f32) ----
  aggregate_kernel<<<aggBlocks, 256, 0, stream>>>(hb2, offsets, csr, meanb, N);
  mfma_gemm_kernel<<<gemmBlocks, 256, 0, stream>>>(meanb, hb2, Wlb2, Wrb2, bl2,
                                                   out, nullptr, N, 0);
}

// Round 6
// 285.743 us; speedup vs baseline: 2.6098x; 1.0902x over previous
//
#include <hip/hip_runtime.h>

#define HID 128

typedef unsigned short ushort_t;
typedef unsigned int uint_t;
typedef float f32x4 __attribute__((ext_vector_type(4)));
typedef short s16x8 __attribute__((ext_vector_type(8)));

__device__ __forceinline__ ushort_t f2bf(float f) {
  uint_t u = __float_as_uint(f);
  uint_t r = (u + 0x7FFFu + ((u >> 16) & 1u)) >> 16;  // RNE
  return (ushort_t)r;
}
__device__ __forceinline__ float bfLo(uint_t v) { return __uint_as_float(v << 16); }
__device__ __forceinline__ float bfHi(uint_t v) { return __uint_as_float(v & 0xFFFF0000u); }

// Bijective XCD swizzle (m204 form): blocks on XCD x = b%8 own a CONTIGUOUS
// region range. Applied consistently to aggregate (meanb writer) and gemm
// (meanb reader) so producer/consumer share an XCD L2 (3.2MB/XCD < 4MB).
// R5 counters: gemm FETCH_SIZE == sizeof(meanb) -> every A-read was a
// cross-XCD L2 miss. Pure index bijection: correctness-neutral.
__device__ __forceinline__ int xcd_region(int b, int nwg) {
  int q = nwg >> 3, r = nwg & 7;
  int x = b & 7, i = b >> 3;
  return x * q + (x < r ? x : r) + i;
}

__device__ __forceinline__ uint4 pack8(const float4& lo, const float4& hi) {
  uint4 p;
  p.x = (uint_t)f2bf(lo.x) | ((uint_t)f2bf(lo.y) << 16);
  p.y = (uint_t)f2bf(lo.z) | ((uint_t)f2bf(lo.w) << 16);
  p.z = (uint_t)f2bf(hi.x) | ((uint_t)f2bf(hi.y) << 16);
  p.w = (uint_t)f2bf(hi.z) | ((uint_t)f2bf(hi.w) << 16);
  return p;
}

// ------- fused prep: 8-deep gather + weight-swizzle + degree count -------
// R9: 1-deep = 43us. R12: 4-deep = 40.8us, VALUBusy 3.6 -> still latency-
// bound. R15: 8 rows/thread, x-loads independent via CLAMP.
// R14 lesson: no grid.sync fusion (coop barrier ~100us/sync on 8 XCDs).
__global__ __launch_bounds__(256) void prep_kernel(
    const float* __restrict__ emb, const int* __restrict__ x,
    ushort_t* __restrict__ hb, int N,
    const float* __restrict__ Wl1, const float* __restrict__ Wr1,
    const float* __restrict__ Wl2, const float* __restrict__ Wr2,
    ushort_t* __restrict__ wsw,
    const int* __restrict__ dst, int* __restrict__ deg, int E) {
  int tid = blockIdx.x * 256 + threadIdx.x;
  const int eN = (N + 7) >> 3;
  int gthreads = eN * 16;
  if (tid < gthreads) {
    int r0 = tid >> 4, j = (tid & 15) * 8;
    int rs[8], si[8];
#pragma unroll
    for (int k = 0; k < 8; k++) {
      int r = r0 + k * eN;
      rs[k] = r;
      int rc = (r < N) ? r : N - 1;
      si[k] = x[rc];  // 8 independent loads
    }
    float4 lo[8], hi[8];
#pragma unroll
    for (int k = 0; k < 8; k++) {
      const float* pk = &emb[(size_t)si[k] * HID + j];
      lo[k] = *(const float4*)pk;
      hi[k] = *(const float4*)(pk + 4);
    }
#pragma unroll
    for (int k = 0; k < 8; k++) {
      if (rs[k] < N)
        *(uint4*)&hb[(size_t)rs[k] * HID + j] = pack8(lo[k], hi[k]);
    }
    return;
  }
  tid -= gthreads;
  if (tid < 65536) {
    const float* srcs[4] = {Wl1, Wr1, Wl2, Wr2};
    int m = tid >> 14, idx = tid & 16383;
    int j = idx & 7;
    int lane = (idx >> 3) & 63;
    int nt = (idx >> 9) & 7;
    int ks = (idx >> 12) & 3;
    int row = nt * 16 + (lane & 15);
    int col = ks * 32 + (lane >> 4) * 8 + j;
    wsw[tid] = f2bf(srcs[m][row * HID + col]);
    return;
  }
  tid -= 65536;
  if (tid < E) atomicAdd(&deg[dst[tid]], 1);
}

// ---------------- CSR build ----------------
__global__ __launch_bounds__(256) void scan1_kernel(
    const int* __restrict__ deg, int* __restrict__ offsets,
    int* __restrict__ sums, int N) {
  __shared__ int s[256];
  int b = blockIdx.x, t = threadIdx.x;
  int base = b * 1024 + t * 4;
  int v0 = 0, v1 = 0, v2 = 0, v3 = 0;
  if (base + 0 < N) v0 = deg[base + 0];
  if (base + 1 < N) v1 = deg[base + 1];
  if (base + 2 < N) v2 = deg[base + 2];
  if (base + 3 < N) v3 = deg[base + 3];
  int mySum = v0 + v1 + v2 + v3;
  s[t] = mySum;
  __syncthreads();
  for (int off = 1; off < 256; off <<= 1) {
    int v = (t >= off) ? s[t - off] : 0;
    __syncthreads();
    s[t] += v;
    __syncthreads();
  }
  int excl = s[t] - mySum;
  if (t == 255) sums[b] = s[255];
  if (base + 0 < N) offsets[base + 0] = excl;
  if (base + 1 < N) offsets[base + 1] = excl + v0;
  if (base + 2 < N) offsets[base + 2] = excl + v0 + v1;
  if (base + 3 < N) offsets[base + 3] = excl + v0 + v1 + v2;
}

__global__ __launch_bounds__(256) void scan3_kernel(
    int* __restrict__ offsets, const int* __restrict__ sums,
    int* __restrict__ cursor, int N, int E, int nb) {
  __shared__ int red[256];
  int t = threadIdx.x;
  int chunk = (blockIdx.x * 256) >> 10;
  red[t] = (t < chunk) ? sums[t] : 0;
  __syncthreads();
  for (int off = 128; off > 0; off >>= 1) {
    if (t < off) red[t] += red[t + off];
    __syncthreads();
  }
  int prefix = red[0];
  int i = blockIdx.x * 256 + t;
  if (i < N) {
    int v = offsets[i] + prefix;
    offsets[i] = v;
    cursor[i] = v;
  } else if (i == N) {
    offsets[N] = E;
  }
}

__global__ __launch_bounds__(256) void fill_kernel(
    const int* __restrict__ src, const int* __restrict__ dst,
    int* __restrict__ cursor, int* __restrict__ csr, int E) {
  int e = blockIdx.x * 256 + threadIdx.x;
  if (e >= E) return;
  int d = dst[e];
  int pos = atomicAdd(&cursor[d], 1);
  csr[pos] = src[e];
}

// ------- aggregate: one node per QUARTER-wave, masked 8-deep batch -------
// R11: gather-latency-bound, needs MAX occupancy -> standalone kernel.
// R13: masked 8-wide batch finishes deg<=8 (~85% at Poisson(6)) in ONE
// dependent csr->hb round. R16: +XCD region swizzle (matched with gemm).
__global__ __launch_bounds__(256) void aggregate_kernel(
    const ushort_t* __restrict__ hb, const int* __restrict__ offsets,
    const int* __restrict__ csr, ushort_t* __restrict__ meanb, int N) {
  int t = threadIdx.x;
  int rIdx = xcd_region(blockIdx.x, gridDim.x);
  int node = rIdx * 16 + (t >> 4);
  if (node >= N) return;
  int l15 = t & 15;
  int o0 = offsets[node], o1 = offsets[node + 1];
  int last = o1 - 1;

  float acc[8];
#pragma unroll
  for (int i = 0; i < 8; i++) acc[i] = 0.f;

  for (int e = o0; e < o1; e += 8) {
    uint4 v[8];
    float m[8];
#pragma unroll
    for (int i = 0; i < 8; i++) {
      int idx = e + i;
      bool val = idx < o1;
      int sidx = csr[val ? idx : last];
      v[i] = *(const uint4*)&hb[(size_t)sidx * HID + l15 * 8];
      m[i] = val ? 1.f : 0.f;
    }
#pragma unroll
    for (int i = 0; i < 8; i++) {
      acc[0] = fmaf(m[i], bfLo(v[i].x), acc[0]);
      acc[1] = fmaf(m[i], bfHi(v[i].x), acc[1]);
      acc[2] = fmaf(m[i], bfLo(v[i].y), acc[2]);
      acc[3] = fmaf(m[i], bfHi(v[i].y), acc[3]);
      acc[4] = fmaf(m[i], bfLo(v[i].z), acc[4]);
      acc[5] = fmaf(m[i], bfHi(v[i].z), acc[5]);
      acc[6] = fmaf(m[i], bfLo(v[i].w), acc[6]);
      acc[7] = fmaf(m[i], bfHi(v[i].w), acc[7]);
    }
  }

  int d = o1 - o0;
  float inv = 1.0f / (float)(d > 1 ? d : 1);
  uint4 p;
  p.x = (uint_t)f2bf(acc[0] * inv) | ((uint_t)f2bf(acc[1] * inv) << 16);
  p.y = (uint_t)f2bf(acc[2] * inv) | ((uint_t)f2bf(acc[3] * inv) << 16);
  p.z = (uint_t)f2bf(acc[4] * inv) | ((uint_t)f2bf(acc[5] * inv) << 16);
  p.w = (uint_t)f2bf(acc[6] * inv) | ((uint_t)f2bf(acc[7] * inv) << 16);
  *(uint4*)&meanb[(size_t)node * HID + l15 * 8] = p;
}

// ---------------- MFMA GEMM (R0/R3 known-good structure) ----------------
// out = relu(mean@Wl^T + h@Wr^T + b). Single 64KB stage, ONE sync.
// R15 lesson: do NOT trade wave count for per-wave tiles (2-tile = 76us).
// R16: +XCD region swizzle matched with aggregate -> meanb reads L2-local.
__global__ __launch_bounds__(256) void mfma_gemm_kernel(
    const ushort_t* __restrict__ meanb, const ushort_t* __restrict__ hb,
    const ushort_t* __restrict__ WlS, const ushort_t* __restrict__ WrS,
    const float* __restrict__ bias, float* __restrict__ outF,
    ushort_t* __restrict__ outB, int N, int outIsBf16) {
  __shared__ ushort_t ws[32768];  // 64 KB: [0..16383]=Wl frags, rest = Wr
  const int t = threadIdx.x;
  const int wave = t >> 6;
  const int lane = t & 63;
  const int rIdx = xcd_region(blockIdx.x, gridDim.x);
  const int rowBase = (rIdx * 4 + wave) * 32;
  const int l15 = lane & 15;
  const int quad = lane >> 4;
  const int kq = quad * 8;
  const bool active = rowBase < N;

  int r0 = rowBase + l15;       if (r0 >= N) r0 = N - 1;
  int r1 = rowBase + 16 + l15;  if (r1 >= N) r1 = N - 1;

  // A-frag prefetch (independent of LDS staging)
  s16x8 a[2][2][4];  // [half][rowgrp][ks]
  if (active) {
#pragma unroll
    for (int ks = 0; ks < 4; ks++) {
      a[0][0][ks] = *(const s16x8*)&meanb[(size_t)r0 * HID + ks * 32 + kq];
      a[0][1][ks] = *(const s16x8*)&meanb[(size_t)r1 * HID + ks * 32 + kq];
      a[1][0][ks] = *(const s16x8*)&hb[(size_t)r0 * HID + ks * 32 + kq];
      a[1][1][ks] = *(const s16x8*)&hb[(size_t)r1 * HID + ks * 32 + kq];
    }
  }

  // stage both weight matrices: contiguous 16B per thread, coalesced
#pragma unroll
  for (int it = 0; it < 8; it++) {
    int o = (it * 256 + t) * 8;
    *(s16x8*)&ws[o] = *(const s16x8*)&WlS[o];
    *(s16x8*)&ws[16384 + o] = *(const s16x8*)&WrS[o];
  }
  __syncthreads();

  if (active) {
    f32x4 acc[2][8];
#pragma unroll
    for (int mt = 0; mt < 2; mt++)
#pragma unroll
      for (int nt = 0; nt < 8; nt++) acc[mt][nt] = (f32x4){0.f, 0.f, 0.f, 0.f};

#pragma unroll
    for (int half = 0; half < 2; half++) {
      const int hbase = half * 16384;
#pragma unroll
      for (int ks = 0; ks < 4; ks++)
#pragma unroll
        for (int nt = 0; nt < 8; nt++) {
          s16x8 bfrag = *(const s16x8*)&ws[hbase + ((ks * 8 + nt) * 64 + lane) * 8];
          acc[0][nt] = __builtin_amdgcn_mfma_f32_16x16x32_bf16(a[half][0][ks], bfrag, acc[0][nt], 0, 0, 0);
          acc[1][nt] = __builtin_amdgcn_mfma_f32_16x16x32_bf16(a[half][1][ks], bfrag, acc[1][nt], 0, 0, 0);
        }
    }

#pragma unroll
    for (int mt = 0; mt < 2; mt++) {
#pragma unroll
      for (int nt = 0; nt < 8; nt++) {
        int col = nt * 16 + l15;
        float bv = bias[col];
#pragma unroll
        for (int r = 0; r < 4; r++) {
          int row = rowBase + mt * 16 + quad * 4 + r;
          if (row < N) {
            float v = fmaxf(acc[mt][nt][r] + bv, 0.f);
            if (outIsBf16) outB[(size_t)row * HID + col] = f2bf(v);
            else           outF[(size_t)row * HID + col] = v;
          }
        }
      }
    }
  }
}

extern "C" void kernel_launch(void* const* d_in, const int* in_sizes, int n_in,
                              void* d_out, int out_size, void* d_ws, size_t ws_size,
                              hipStream_t stream) {
  const int* x = (const int*)d_in[0];
  const int* ei = (const int*)d_in[1];
  const float* emb = (const float*)d_in[2];
  const float* Wl1 = (const float*)d_in[3];
  const float* bl1 = (const float*)d_in[4];
  const float* Wr1 = (const float*)d_in[5];
  const float* Wl2 = (const float*)d_in[6];
  const float* bl2 = (const float*)d_in[7];
  const float* Wr2 = (const float*)d_in[8];
  float* out = (float*)d_out;

  const int N = in_sizes[0];
  const int E = in_sizes[1] / 2;
  const int* srcI = ei;
  const int* dstI = ei + E;

  // workspace layout
  char* p = (char*)d_ws;
  ushort_t* hb = (ushort_t*)p;    p += (size_t)N * HID * sizeof(ushort_t);
  ushort_t* hb2 = (ushort_t*)p;   p += (size_t)N * HID * sizeof(ushort_t);
  ushort_t* meanb = (ushort_t*)p; p += (size_t)N * HID * sizeof(ushort_t);
  ushort_t* wb = (ushort_t*)p;    p += (size_t)4 * 16384 * sizeof(ushort_t);
  int* deg = (int*)p;             p += (size_t)((N + 3) & ~3) * sizeof(int);
  int* offsets = (int*)p;         p += (size_t)((N + 4) & ~3) * sizeof(int);
  int* cursor = (int*)p;          p += (size_t)((N + 3) & ~3) * sizeof(int);
  int* csr = (int*)p;             p += (size_t)((E + 3) & ~3) * sizeof(int);
  int* sums = (int*)p;            p += 256 * sizeof(int);

  ushort_t* Wlb1 = wb;
  ushort_t* Wrb1 = wb + 16384;
  ushort_t* Wlb2 = wb + 32768;
  ushort_t* Wrb2 = wb + 49152;

  const int nScanBlocks = (N + 1023) / 1024;  // <=256 required
  const int eBlocks = (E + 255) / 256;
  const int gemmBlocks = (N + 127) / 128;
  const int aggBlocks = (N + 15) / 16;
  const int eN = (N + 7) / 8;
  const int prepBlocks = (eN * 16 + 65536 + E + 255) / 256;

  // ---- CSR build + conversions ----
  hipMemsetAsync(deg, 0, (size_t)N * sizeof(int), stream);
  prep_kernel<<<prepBlocks, 256, 0, stream>>>(emb, x, hb, N,
                                              Wl1, Wr1, Wl2, Wr2, wb,
                                              dstI, deg, E);
  scan1_kernel<<<nScanBlocks, 256, 0, stream>>>(deg, offsets, sums, N);
  scan3_kernel<<<(N + 256) / 256, 256, 0, stream>>>(offsets, sums, cursor,
                                                    N, E, nScanBlocks);
  fill_kernel<<<eBlocks, 256, 0, stream>>>(srcI, dstI, cursor, csr, E);

  // ---- layer 1: hb -> hb2 (bf16) ----
  aggregate_kernel<<<aggBlocks, 256, 0, stream>>>(hb, offsets, csr, meanb, N);
  mfma_gemm_kernel<<<gemmBlocks, 256, 0, stream>>>(meanb, hb, Wlb1, Wrb1, bl1,
                                                   nullptr, hb2, N, 1);

  // ---- layer 2: hb2 -> out (f32) ----
  aggregate_kernel<<<aggBlocks, 256, 0, stream>>>(hb2, offsets, csr, meanb, N);
  mfma_gemm_kernel<<<gemmBlocks, 256, 0, stream>>>(meanb, hb2, Wlb2, Wrb2, bl2,
                                                   out, nullptr, N, 0);
}

// Round 7
// 272.612 us; speedup vs baseline: 2.7355x; 1.0482x over previous
//
#include <hip/hip_runtime.h>

#define HID 128

typedef unsigned short ushort_t;
typedef unsigned int uint_t;
typedef float f32x4 __attribute__((ext_vector_type(4)));
typedef short s16x8 __attribute__((ext_vector_type(8)));

__device__ __forceinline__ ushort_t f2bf(float f) {
  uint_t u = __float_as_uint(f);
  uint_t r = (u + 0x7FFFu + ((u >> 16) & 1u)) >> 16;  // RNE
  return (ushort_t)r;
}
__device__ __forceinline__ float bfLo(uint_t v) { return __uint_as_float(v << 16); }
__device__ __forceinline__ float bfHi(uint_t v) { return __uint_as_float(v & 0xFFFF0000u); }

__device__ __forceinline__ uint4 pack8(const float4& lo, const float4& hi) {
  uint4 p;
  p.x = (uint_t)f2bf(lo.x) | ((uint_t)f2bf(lo.y) << 16);
  p.y = (uint_t)f2bf(lo.z) | ((uint_t)f2bf(lo.w) << 16);
  p.z = (uint_t)f2bf(hi.x) | ((uint_t)f2bf(hi.y) << 16);
  p.w = (uint_t)f2bf(hi.z) | ((uint_t)f2bf(hi.w) << 16);
  return p;
}

// ------- fused prep: 8-deep gather + weight-swizzle + degree count -------
// R9: 1-deep = 43us. R12: 4-deep = 40.8us. R15: 8-deep (clamped independent
// x-loads) -> out of top-5, ~10us saved (R6 accounting).
// R14 lesson: no grid.sync fusion (coop barrier ~100us/sync on 8 XCDs).
__global__ __launch_bounds__(256) void prep_kernel(
    const float* __restrict__ emb, const int* __restrict__ x,
    ushort_t* __restrict__ hb, int N,
    const float* __restrict__ Wl1, const float* __restrict__ Wr1,
    const float* __restrict__ Wl2, const float* __restrict__ Wr2,
    ushort_t* __restrict__ wsw,
    const int* __restrict__ dst, int* __restrict__ deg, int E) {
  int tid = blockIdx.x * 256 + threadIdx.x;
  const int eN = (N + 7) >> 3;
  int gthreads = eN * 16;
  if (tid < gthreads) {
    int r0 = tid >> 4, j = (tid & 15) * 8;
    int rs[8], si[8];
#pragma unroll
    for (int k = 0; k < 8; k++) {
      int r = r0 + k * eN;
      rs[k] = r;
      int rc = (r < N) ? r : N - 1;
      si[k] = x[rc];  // 8 independent loads
    }
    float4 lo[8], hi[8];
#pragma unroll
    for (int k = 0; k < 8; k++) {
      const float* pk = &emb[(size_t)si[k] * HID + j];
      lo[k] = *(const float4*)pk;
      hi[k] = *(const float4*)(pk + 4);
    }
#pragma unroll
    for (int k = 0; k < 8; k++) {
      if (rs[k] < N)
        *(uint4*)&hb[(size_t)rs[k] * HID + j] = pack8(lo[k], hi[k]);
    }
    return;
  }
  tid -= gthreads;
  if (tid < 65536) {
    const float* srcs[4] = {Wl1, Wr1, Wl2, Wr2};
    int m = tid >> 14, idx = tid & 16383;
    int j = idx & 7;
    int lane = (idx >> 3) & 63;
    int nt = (idx >> 9) & 7;
    int ks = (idx >> 12) & 3;
    int row = nt * 16 + (lane & 15);
    int col = ks * 32 + (lane >> 4) * 8 + j;
    wsw[tid] = f2bf(srcs[m][row * HID + col]);
    return;
  }
  tid -= 65536;
  if (tid < E) atomicAdd(&deg[dst[tid]], 1);
}

// ---------------- CSR build ----------------
__global__ __launch_bounds__(256) void scan1_kernel(
    const int* __restrict__ deg, int* __restrict__ offsets,
    int* __restrict__ sums, int N) {
  __shared__ int s[256];
  int b = blockIdx.x, t = threadIdx.x;
  int base = b * 1024 + t * 4;
  int v0 = 0, v1 = 0, v2 = 0, v3 = 0;
  if (base + 0 < N) v0 = deg[base + 0];
  if (base + 1 < N) v1 = deg[base + 1];
  if (base + 2 < N) v2 = deg[base + 2];
  if (base + 3 < N) v3 = deg[base + 3];
  int mySum = v0 + v1 + v2 + v3;
  s[t] = mySum;
  __syncthreads();
  for (int off = 1; off < 256; off <<= 1) {
    int v = (t >= off) ? s[t - off] : 0;
    __syncthreads();
    s[t] += v;
    __syncthreads();
  }
  int excl = s[t] - mySum;
  if (t == 255) sums[b] = s[255];
  if (base + 0 < N) offsets[base + 0] = excl;
  if (base + 1 < N) offsets[base + 1] = excl + v0;
  if (base + 2 < N) offsets[base + 2] = excl + v0 + v1;
  if (base + 3 < N) offsets[base + 3] = excl + v0 + v1 + v2;
}

__global__ __launch_bounds__(256) void scan3_kernel(
    int* __restrict__ offsets, const int* __restrict__ sums,
    int* __restrict__ cursor, int N, int E, int nb) {
  __shared__ int red[256];
  int t = threadIdx.x;
  int chunk = (blockIdx.x * 256) >> 10;
  red[t] = (t < chunk) ? sums[t] : 0;
  __syncthreads();
  for (int off = 128; off > 0; off >>= 1) {
    if (t < off) red[t] += red[t + off];
    __syncthreads();
  }
  int prefix = red[0];
  int i = blockIdx.x * 256 + t;
  if (i < N) {
    int v = offsets[i] + prefix;
    offsets[i] = v;
    cursor[i] = v;
  } else if (i == N) {
    offsets[N] = E;
  }
}

__global__ __launch_bounds__(256) void fill_kernel(
    const int* __restrict__ src, const int* __restrict__ dst,
    int* __restrict__ cursor, int* __restrict__ csr, int E) {
  int e = blockIdx.x * 256 + threadIdx.x;
  if (e >= E) return;
  int d = dst[e];
  int pos = atomicAdd(&cursor[d], 1);
  csr[pos] = src[e];
}

// ------- aggregate: one node per QUARTER-wave, masked 8-deep batch -------
// R11: gather-latency-bound, needs MAX occupancy -> standalone kernel.
// R13: masked 8-wide batch finishes deg<=8 (~85% at Poisson(6)) in ONE
// dependent csr->hb round. R17: swizzle REMOVED (R6: no FETCH change --
// L2 doesn't survive dispatch boundaries; scattering hurt L3 locality).
__global__ __launch_bounds__(256) void aggregate_kernel(
    const ushort_t* __restrict__ hb, const int* __restrict__ offsets,
    const int* __restrict__ csr, ushort_t* __restrict__ meanb, int N) {
  int t = threadIdx.x;
  int node = blockIdx.x * 16 + (t >> 4);
  if (node >= N) return;
  int l15 = t & 15;
  int o0 = offsets[node], o1 = offsets[node + 1];
  int last = o1 - 1;

  float acc[8];
#pragma unroll
  for (int i = 0; i < 8; i++) acc[i] = 0.f;

  for (int e = o0; e < o1; e += 8) {
    uint4 v[8];
    float m[8];
#pragma unroll
    for (int i = 0; i < 8; i++) {
      int idx = e + i;
      bool val = idx < o1;
      int sidx = csr[val ? idx : last];
      v[i] = *(const uint4*)&hb[(size_t)sidx * HID + l15 * 8];
      m[i] = val ? 1.f : 0.f;
    }
#pragma unroll
    for (int i = 0; i < 8; i++) {
      acc[0] = fmaf(m[i], bfLo(v[i].x), acc[0]);
      acc[1] = fmaf(m[i], bfHi(v[i].x), acc[1]);
      acc[2] = fmaf(m[i], bfLo(v[i].y), acc[2]);
      acc[3] = fmaf(m[i], bfHi(v[i].y), acc[3]);
      acc[4] = fmaf(m[i], bfLo(v[i].z), acc[4]);
      acc[5] = fmaf(m[i], bfHi(v[i].z), acc[5]);
      acc[6] = fmaf(m[i], bfLo(v[i].w), acc[6]);
      acc[7] = fmaf(m[i], bfHi(v[i].w), acc[7]);
    }
  }

  int d = o1 - o0;
  float inv = 1.0f / (float)(d > 1 ? d : 1);
  uint4 p;
  p.x = (uint_t)f2bf(acc[0] * inv) | ((uint_t)f2bf(acc[1] * inv) << 16);
  p.y = (uint_t)f2bf(acc[2] * inv) | ((uint_t)f2bf(acc[3] * inv) << 16);
  p.z = (uint_t)f2bf(acc[4] * inv) | ((uint_t)f2bf(acc[5] * inv) << 16);
  p.w = (uint_t)f2bf(acc[6] * inv) | ((uint_t)f2bf(acc[7] * inv) << 16);
  *(uint4*)&meanb[(size_t)node * HID + l15 * 8] = p;
}

// ---------------- MFMA GEMM: out = relu(mean@Wl^T + h@Wr^T + b) ----------------
// R13 lesson: single 64KB stage, ONE sync (both matrices' loads in flight).
// R15 lesson: never trade wave count for per-wave tiles (latency-bound).
// R17: 512-thread blocks (8 waves x 32 rows). LDS is the binding constraint
// (64KB -> 2 blk/CU) either way, so 512t doubles resident waves: 8->16/CU.
// Per-wave code identical to the known-good R0/R3 shape. launch_bounds
// (512,4) pins VGPR<=128 so 4 waves/SIMD fit.
__global__ __launch_bounds__(512, 4) void mfma_gemm_kernel(
    const ushort_t* __restrict__ meanb, const ushort_t* __restrict__ hb,
    const ushort_t* __restrict__ WlS, const ushort_t* __restrict__ WrS,
    const float* __restrict__ bias, float* __restrict__ outF,
    ushort_t* __restrict__ outB, int N, int outIsBf16) {
  __shared__ ushort_t ws[32768];  // 64 KB: [0..16383]=Wl frags, rest = Wr
  const int t = threadIdx.x;
  const int wave = t >> 6;   // 0..7
  const int lane = t & 63;
  const int rowBase = (blockIdx.x * 8 + wave) * 32;
  const int l15 = lane & 15;
  const int quad = lane >> 4;
  const int kq = quad * 8;
  const bool active = rowBase < N;

  int r0 = rowBase + l15;       if (r0 >= N) r0 = N - 1;
  int r1 = rowBase + 16 + l15;  if (r1 >= N) r1 = N - 1;

  // A-frag prefetch (independent of LDS staging)
  s16x8 a[2][2][4];  // [half][rowgrp][ks]
  if (active) {
#pragma unroll
    for (int ks = 0; ks < 4; ks++) {
      a[0][0][ks] = *(const s16x8*)&meanb[(size_t)r0 * HID + ks * 32 + kq];
      a[0][1][ks] = *(const s16x8*)&meanb[(size_t)r1 * HID + ks * 32 + kq];
      a[1][0][ks] = *(const s16x8*)&hb[(size_t)r0 * HID + ks * 32 + kq];
      a[1][1][ks] = *(const s16x8*)&hb[(size_t)r1 * HID + ks * 32 + kq];
    }
  }

  // stage both weight matrices: contiguous 16B per thread, coalesced
#pragma unroll
  for (int it = 0; it < 4; it++) {
    int o = (it * 512 + t) * 8;
    *(s16x8*)&ws[o] = *(const s16x8*)&WlS[o];
    *(s16x8*)&ws[16384 + o] = *(const s16x8*)&WrS[o];
  }
  __syncthreads();

  if (active) {
    f32x4 acc[2][8];
#pragma unroll
    for (int mt = 0; mt < 2; mt++)
#pragma unroll
      for (int nt = 0; nt < 8; nt++) acc[mt][nt] = (f32x4){0.f, 0.f, 0.f, 0.f};

#pragma unroll
    for (int half = 0; half < 2; half++) {
      const int hbase = half * 16384;
#pragma unroll
      for (int ks = 0; ks < 4; ks++)
#pragma unroll
        for (int nt = 0; nt < 8; nt++) {
          s16x8 bfrag = *(const s16x8*)&ws[hbase + ((ks * 8 + nt) * 64 + lane) * 8];
          acc[0][nt] = __builtin_amdgcn_mfma_f32_16x16x32_bf16(a[half][0][ks], bfrag, acc[0][nt], 0, 0, 0);
          acc[1][nt] = __builtin_amdgcn_mfma_f32_16x16x32_bf16(a[half][1][ks], bfrag, acc[1][nt], 0, 0, 0);
        }
    }

#pragma unroll
    for (int mt = 0; mt < 2; mt++) {
#pragma unroll
      for (int nt = 0; nt < 8; nt++) {
        int col = nt * 16 + l15;
        float bv = bias[col];
#pragma unroll
        for (int r = 0; r < 4; r++) {
          int row = rowBase + mt * 16 + quad * 4 + r;
          if (row < N) {
            float v = fmaxf(acc[mt][nt][r] + bv, 0.f);
            if (outIsBf16) outB[(size_t)row * HID + col] = f2bf(v);
            else           outF[(size_t)row * HID + col] = v;
          }
        }
      }
    }
  }
}

extern "C" void kernel_launch(void* const* d_in, const int* in_sizes, int n_in,
                              void* d_out, int out_size, void* d_ws, size_t ws_size,
                              hipStream_t stream) {
  const int* x = (const int*)d_in[0];
  const int* ei = (const int*)d_in[1];
  const float* emb = (const float*)d_in[2];
  const float* Wl1 = (const float*)d_in[3];
  const float* bl1 = (const float*)d_in[4];
  const float* Wr1 = (const float*)d_in[5];
  const float* Wl2 = (const float*)d_in[6];
  const float* bl2 = (const float*)d_in[7];
  const float* Wr2 = (const float*)d_in[8];
  float* out = (float*)d_out;

  const int N = in_sizes[0];
  const int E = in_sizes[1] / 2;
  const int* srcI = ei;
  const int* dstI = ei + E;

  // workspace layout
  char* p = (char*)d_ws;
  ushort_t* hb = (ushort_t*)p;    p += (size_t)N * HID * sizeof(ushort_t);
  ushort_t* hb2 = (ushort_t*)p;   p += (size_t)N * HID * sizeof(ushort_t);
  ushort_t* meanb = (ushort_t*)p; p += (size_t)N * HID * sizeof(ushort_t);
  ushort_t* wb = (ushort_t*)p;    p += (size_t)4 * 16384 * sizeof(ushort_t);
  int* deg = (int*)p;             p += (size_t)((N + 3) & ~3) * sizeof(int);
  int* offsets = (int*)p;         p += (size_t)((N + 4) & ~3) * sizeof(int);
  int* cursor = (int*)p;          p += (size_t)((N + 3) & ~3) * sizeof(int);
  int* csr = (int*)p;             p += (size_t)((E + 3) & ~3) * sizeof(int);
  int* sums = (int*)p;            p += 256 * sizeof(int);

  ushort_t* Wlb1 = wb;
  ushort_t* Wrb1 = wb + 16384;
  ushort_t* Wlb2 = wb + 32768;
  ushort_t* Wrb2 = wb + 49152;

  const int nScanBlocks = (N + 1023) / 1024;  // <=256 required
  const int eBlocks = (E + 255) / 256;
  const int gemmBlocks = (N + 255) / 256;     // 512 threads, 256 rows/block
  const int aggBlocks = (N + 15) / 16;
  const int eN = (N + 7) / 8;
  const int prepBlocks = (eN * 16 + 65536 + E + 255) / 256;

  // ---- CSR build + conversions ----
  hipMemsetAsync(deg, 0, (size_t)N * sizeof(int), stream);
  prep_kernel<<<prepBlocks, 256, 0, stream>>>(emb, x, hb, N,
                                              Wl1, Wr1, Wl2, Wr2, wb,
                                              dstI, deg, E);
  scan1_kernel<<<nScanBlocks, 256, 0, stream>>>(deg, offsets, sums, N);
  scan3_kernel<<<(N + 256) / 256, 256, 0, stream>>>(offsets, sums, cursor,
                                                    N, E, nScanBlocks);
  fill_kernel<<<eBlocks, 256, 0, stream>>>(srcI, dstI, cursor, csr, E);

  // ---- layer 1: hb -> hb2 (bf16) ----
  aggregate_kernel<<<aggBlocks, 256, 0, stream>>>(hb, offsets, csr, meanb, N);
  mfma_gemm_kernel<<<gemmBlocks, 512, 0, stream>>>(meanb, hb, Wlb1, Wrb1, bl1,
                                                   nullptr, hb2, N, 1);

  // ---- layer 2: hb2 -> out (f32) ----
  aggregate_kernel<<<aggBlocks, 256, 0, stream>>>(hb2, offsets, csr, meanb, N);
  mfma_gemm_kernel<<<gemmBlocks, 512, 0, stream>>>(meanb, hb2, Wlb2, Wrb2, bl2,
                                                   out, nullptr, N, 0);
}